// Round 10
// baseline (883.249 us; speedup 1.0000x reference)
//
#include <hip/hip_runtime.h>
#include <hip/hip_bf16.h>

// ---------- types ----------
typedef __bf16 bf16x8 __attribute__((ext_vector_type(8)));
typedef float  f32x4  __attribute__((ext_vector_type(4)));
typedef float  f32x4v __attribute__((ext_vector_type(4)));

#define LOG2E 1.44269504088896340736f

static __device__ __forceinline__ f32x4 mfma16(bf16x8 a, bf16x8 b, f32x4 c) {
    return __builtin_amdgcn_mfma_f32_16x16x32_bf16(a, b, c, 0, 0, 0);
}

static __device__ __forceinline__ void gload_lds16(const void* g, void* lds) {
    __builtin_amdgcn_global_load_lds(
        (const __attribute__((address_space(1))) void*)g,
        (__attribute__((address_space(3))) void*)lds, 16, 0, 0);
}

// ---------- fused weight transpose (all three), bf16 ----------
// Wq [512][512] scaled; Wk,Wv [768][512]. grid 4096*256 == 1048576.
__global__ void wtrans_all(const float* __restrict__ Wq, const float* __restrict__ Wk,
                           const float* __restrict__ Wv, __bf16* __restrict__ WqT,
                           __bf16* __restrict__ WkT, __bf16* __restrict__ WvT) {
    int idx = blockIdx.x * 256 + threadIdx.x;
    if (idx < 262144) {
        int k = idx >> 9, n = idx & 511;
        WqT[(size_t)n * 512 + k] = (__bf16)(Wq[idx] * 0.044194173824159216f);
    } else if (idx < 655360) {
        int i = idx - 262144;
        int k = i >> 9, n = i & 511;
        WkT[(size_t)n * 768 + k] = (__bf16)Wk[i];
    } else {
        int i = idx - 655360;
        int k = i >> 9, n = i & 511;
        WvT[(size_t)n * 768 + k] = (__bf16)Wv[i];
    }
}

// ---------- 128x128-tile GEMM, BK=64, dbuf; one operand f32 (reg-staged + cvt),
// the other bf16 (global_load_lds). C[m][n] = sum_k A[m][k]*B[n][k].
// AF32: A is the f32 side (else B). MODE 0: C bf16 [M][512]. MODE 1: VT layout.
template<int MODE, bool AF32>
__global__ __launch_bounds__(256, 2) void gemm128(
    const void* __restrict__ Ap, const void* __restrict__ Bp,
    __bf16* __restrict__ C, int Ktot, size_t sAz, size_t sBz) {
    __shared__ char smem[65536];
    const int tid = threadIdx.x, w = tid >> 6, lane = tid & 63;
    const int r = lane & 15, g = lane >> 4;
    const int wr = w >> 1, wc = w & 1;
    const int m0 = blockIdx.y * 128, n0 = blockIdx.x * 128;
    const int z = blockIdx.z;

    // F = f32 side (reg-staged), G = bf16 side (gload_lds)
    const float*  F = AF32 ? (const float*)Ap + sAz * z : (const float*)Bp + sBz * z;
    const __bf16* G = AF32 ? (const __bf16*)Bp + sBz * z : (const __bf16*)Ap + sAz * z;
    const int Fbase = AF32 ? m0 : n0;
    const int Gbase = AF32 ? n0 : m0;

    f32x4 acc[4][4];
#pragma unroll
    for (int i = 0; i < 4; ++i)
#pragma unroll
        for (int j = 0; j < 4; ++j) acc[i][j] = (f32x4){0.f, 0.f, 0.f, 0.f};

    const int nsteps = Ktot >> 6;
    f32x4v rg[8];

    auto ISSUE = [&](int t) {
        int k0 = t * 64;
#pragma unroll
        for (int e = 0; e < 4; ++e) {           // 8 global f32x4 loads (F side)
            int flat = tid + e * 256;
            int row = flat >> 3, blk = flat & 7;
            const float* gp = F + (size_t)(Fbase + row) * Ktot + k0 + blk * 8;
            rg[2 * e]     = *(const f32x4v*)gp;
            rg[2 * e + 1] = *(const f32x4v*)(gp + 4);
        }
        char* bufG = smem + (t & 1) * 32768 + (AF32 ? 16384 : 0);
#pragma unroll
        for (int e = 0; e < 4; ++e) {           // 4 gload_lds (G side)
            int rows8 = w * 32 + e * 8;
            int row = rows8 + (lane >> 3);
            int so = ((lane & 7) ^ (row & 7)) << 4;
            gload_lds16((const char*)(G + (size_t)(Gbase + row) * Ktot + k0) + so,
                        bufG + rows8 * 128);
        }
    };
    auto WRITE = [&](int t) {
        char* bufF = smem + (t & 1) * 32768 + (AF32 ? 0 : 16384);
#pragma unroll
        for (int e = 0; e < 4; ++e) {
            int flat = tid + e * 256;
            int row = flat >> 3, blk = flat & 7;
            bf16x8 v;
            v[0] = (__bf16)rg[2 * e][0]; v[1] = (__bf16)rg[2 * e][1];
            v[2] = (__bf16)rg[2 * e][2]; v[3] = (__bf16)rg[2 * e][3];
            v[4] = (__bf16)rg[2 * e + 1][0]; v[5] = (__bf16)rg[2 * e + 1][1];
            v[6] = (__bf16)rg[2 * e + 1][2]; v[7] = (__bf16)rg[2 * e + 1][3];
            *(bf16x8*)(bufF + row * 128 + ((blk ^ (row & 7)) << 4)) = v;
        }
    };

    ISSUE(0);
#pragma unroll 1
    for (int t = 0; t < nsteps; ++t) {
        __builtin_amdgcn_s_barrier();                       // buf[(t+1)&1] free
        asm volatile("s_waitcnt vmcnt(4)" ::: "memory");    // F(t) reg-loads landed
        WRITE(t);
        if (t + 1 < nsteps) {
            ISSUE(t + 1);
            asm volatile("s_waitcnt vmcnt(12)" ::: "memory"); // G(t) gloads landed
        } else {
            asm volatile("s_waitcnt vmcnt(0)" ::: "memory");
        }
        asm volatile("s_waitcnt lgkmcnt(0)" ::: "memory");    // ds_writes visible
        __builtin_amdgcn_s_barrier();                       // tile t ready
        __builtin_amdgcn_sched_barrier(0);

        char* bufA = smem + (t & 1) * 32768;
        char* bufB = bufA + 16384;
#pragma unroll
        for (int c = 0; c < 2; ++c) {
            bf16x8 a[4], bb[4];
#pragma unroll
            for (int mt = 0; mt < 4; ++mt) {
                int ar = wr * 64 + mt * 16 + r;
                a[mt] = *(const bf16x8*)(bufA + ar * 128 + (((c * 4 + g) ^ (ar & 7)) << 4));
            }
#pragma unroll
            for (int nt = 0; nt < 4; ++nt) {
                int br = wc * 64 + nt * 16 + r;
                bb[nt] = *(const bf16x8*)(bufB + br * 128 + (((c * 4 + g) ^ (br & 7)) << 4));
            }
            __builtin_amdgcn_s_setprio(1);
#pragma unroll
            for (int mt = 0; mt < 4; ++mt)
#pragma unroll
                for (int nt = 0; nt < 4; ++nt)
                    acc[mt][nt] = mfma16(a[mt], bb[nt], acc[mt][nt]);
            __builtin_amdgcn_s_setprio(0);
        }
    }

#pragma unroll
    for (int mt = 0; mt < 4; ++mt)
#pragma unroll
        for (int nt = 0; nt < 4; ++nt)
#pragma unroll
            for (int j = 0; j < 4; ++j) {
                int m = m0 + wr * 64 + mt * 16 + g * 4 + j;
                int n = n0 + wc * 64 + nt * 16 + r;
                if (MODE == 0) {
                    C[(size_t)m * 512 + n] = (__bf16)acc[mt][nt][j];
                } else {
                    int l = n & 31;
                    int perm = ((l >> 2) & 3) * 8 + ((l >> 4) & 1) * 4 + (l & 3);
                    C[(((size_t)z * 32 + (n >> 5)) * 512 + m) * 32 + perm] =
                        (__bf16)acc[mt][nt][j];
                }
            }
}

// ---------- flash attention ----------
// grid (32, 8): qb = blockIdx.x, b = blockIdx.y (r3/r7 mapping — FETCH ~85 MB).
// block 512 = 8 waves; wave w owns q rows [qb*128+16w, +16). KVBLK=32.
// LDS 160 KB: K dbuf 2x32KB at [0,64K); V tri-buf 3x32KB at [64K,160K).
//   K [32 s][1024B] swz ^((row&7)<<4); VT [512 h][64B] interleaved-s,
//   blk swz ^((vrow>>1)&3).
// T15 deferred-PV: iter t computes QK(t)+softmax(t) but applies PV(t-1) with
// saved {pa,corr4,skip} — softmax VALU and PV LDS/MFMA are independent chains,
// scheduler interleaves them. V tri-buffer makes V(t-1) safe while V(t+1)
// stages: writer of Vbuf[(t+2)%3] at iter t+1 is barrier-ordered after its
// readers (PV(t-1) at iter t). vmcnt(8) waits K(t+1) => all older V landed.
// r4-r6 lesson: no extra live softmax state; rescale-skip is branch-only
// (bit-exact: skip => mnew==mrun, corr==1).
__global__ __launch_bounds__(512, 2) void flash_kernel(
    const __bf16* __restrict__ Q,    // [B*4096][512] (pre-scaled by 1/sqrt(512))
    const __bf16* __restrict__ Kg,   // [B*1024][512]
    const __bf16* __restrict__ VT,   // [B][32][512 h][32 s interleaved]
    float* __restrict__ O) {         // [B*4096][512]
    __shared__ char smem[163840];

    const int tid = threadIdx.x, w = tid >> 6, lane = tid & 63;
    const int r = lane & 15, g = lane >> 4;
    const int b = blockIdx.y, qb = blockIdx.x;

    const __bf16* Qrow = Q + ((size_t)b * 4096 + qb * 128 + w * 16 + r) * 512;
    bf16x8 q[16];
#pragma unroll
    for (int c = 0; c < 16; ++c) q[c] = *(const bf16x8*)(Qrow + c * 32 + g * 8);

    f32x4 acc[32];
#pragma unroll
    for (int i = 0; i < 32; ++i) acc[i] = (f32x4){0.f, 0.f, 0.f, 0.f};

    float mrun = -__builtin_inff(), lrun = 0.f;

    const size_t kbase = (size_t)b * 1024 * 512;
    const char*  vbase = (const char*)(VT + (size_t)b * 32 * 16384);

    auto STAGE = [&](int it, int vidx) {
        char* kb = smem + (it & 1) * 32768;
        const char* ksrc = (const char*)(Kg + kbase + (size_t)it * 32 * 512);
#pragma unroll
        for (int e = 0; e < 4; ++e) {
            int row = w * 4 + e;
            gload_lds16(ksrc + row * 1024 + ((lane * 16) ^ ((row & 7) << 4)),
                        kb + row * 1024);
        }
        char* vb = smem + 65536 + vidx * 32768;
        const char* vtile = vbase + (size_t)it * 32768;
#pragma unroll
        for (int e = 0; e < 4; ++e) {
            int flat = e * 512 + w * 64 + lane;
            int vrow = flat >> 2, blk = flat & 3;
            gload_lds16(vtile + vrow * 64 + ((blk ^ ((vrow >> 1) & 3)) << 4),
                        vb + e * 8192 + w * 1024);             // +lane*16 by HW
        }
    };

    // deferred-PV state (P/corr of tile t-1)
    union { bf16x8 v; __bf16 e[8]; } pa_prev;
#pragma unroll
    for (int j = 0; j < 8; ++j) pa_prev.e[j] = (__bf16)0.f;
    float corr4_prev[4] = {1.f, 1.f, 1.f, 1.f};
    bool skip_prev = true;

    auto DO_PV = [&](const char* Vt) {
        __builtin_amdgcn_s_setprio(1);
        if (skip_prev) {
#pragma unroll
            for (int ht = 0; ht < 32; ++ht) {
                int vrow = ht * 16 + r;
                bf16x8 bv = *(const bf16x8*)(Vt + vrow * 64 + ((g ^ ((r >> 1) & 3)) << 4));
                acc[ht] = mfma16(pa_prev.v, bv, acc[ht]);
            }
        } else {
#pragma unroll
            for (int ht = 0; ht < 32; ++ht) {
                int vrow = ht * 16 + r;
                bf16x8 bv = *(const bf16x8*)(Vt + vrow * 64 + ((g ^ ((r >> 1) & 3)) << 4));
                f32x4 a = acc[ht];
                a[0] *= corr4_prev[0]; a[1] *= corr4_prev[1];
                a[2] *= corr4_prev[2]; a[3] *= corr4_prev[3];
                acc[ht] = mfma16(pa_prev.v, bv, a);
            }
        }
        __builtin_amdgcn_s_setprio(0);
    };

    STAGE(0, 0);
    int vprev = 2, vcur = 0, vnext = 1;   // (t-1)%3, t%3, (t+1)%3

#pragma unroll 1
    for (int it = 0; it < 32; ++it) {
        __builtin_amdgcn_s_barrier();   // readers of Kbuf[(it+1)&1], Vbuf[vnext] done
        if (it < 31) {
            STAGE(it + 1, vnext);
            asm volatile("s_waitcnt vmcnt(8)" ::: "memory");  // K(it) .. K(it+1) landed
        } else {
            asm volatile("s_waitcnt vmcnt(0)" ::: "memory");
        }
        __builtin_amdgcn_s_barrier();   // all waves' tile-it landed
        __builtin_amdgcn_sched_barrier(0);

        char* Kt = smem + (it & 1) * 32768;

        // QK^T(it): S^T[s][q] = mfma(Kfrag, Qfrag); q = r, s: sc0->4g+j, sc1->16+4g+j
        f32x4 sc0 = (f32x4){0.f, 0.f, 0.f, 0.f};
        f32x4 sc1 = (f32x4){0.f, 0.f, 0.f, 0.f};
        const int sw = (r & 7) << 4;   // (r+16)&7 == r&7
        __builtin_amdgcn_s_setprio(1);
#pragma unroll
        for (int c = 0; c < 16; ++c) {
            int bir = (c * 64 + g * 16) ^ sw;
            bf16x8 k0 = *(const bf16x8*)(Kt + r * 1024 + bir);
            bf16x8 k1 = *(const bf16x8*)(Kt + (r + 16) * 1024 + bir);
            sc0 = mfma16(k0, q[c], sc0);
            sc1 = mfma16(k1, q[c], sc1);
        }
        __builtin_amdgcn_s_setprio(0);

        // softmax(it) for q = r; bit-exact rescale skip when no row max grew
        float mt = fmaxf(fmaxf(fmaxf(sc0[0], sc0[1]), fmaxf(sc0[2], sc0[3])),
                         fmaxf(fmaxf(sc1[0], sc1[1]), fmaxf(sc1[2], sc1[3])));
        mt = fmaxf(mt, __shfl_xor(mt, 16, 64));
        mt = fmaxf(mt, __shfl_xor(mt, 32, 64));

        const bool skip = __all(mt <= mrun);
        const float mnew = skip ? mrun : fmaxf(mrun, mt);
        float p0[4], p1[4], ps = 0.f;
#pragma unroll
        for (int j = 0; j < 4; ++j) {
            p0[j] = exp2f((sc0[j] - mnew) * LOG2E);
            p1[j] = exp2f((sc1[j] - mnew) * LOG2E);
            ps += p0[j] + p1[j];
        }
        ps += __shfl_xor(ps, 16, 64);
        ps += __shfl_xor(ps, 32, 64);
        float corr = 1.f;
        if (skip) {
            lrun += ps;
        } else {
            corr = exp2f((mrun - mnew) * LOG2E);
            lrun = lrun * corr + ps;
            mrun = mnew;
        }

        // deferred PV(it-1) — independent of softmax(it); scheduler interleaves
        if (it) DO_PV(smem + 65536 + vprev * 32768);

        // save state for next iter
        skip_prev = skip;
        if (!skip) {
#pragma unroll
            for (int j = 0; j < 4; ++j) corr4_prev[j] = __shfl(corr, g * 4 + j, 64);
        }
#pragma unroll
        for (int j = 0; j < 4; ++j) {
            pa_prev.e[j] = (__bf16)p0[j]; pa_prev.e[4 + j] = (__bf16)p1[j];
        }

        int t0 = vprev; vprev = vcur; vcur = vnext; vnext = t0;
    }

    // epilogue: PV(31)
    DO_PV(smem + 65536 + vprev * 32768);

    float rl[4];
#pragma unroll
    for (int j = 0; j < 4; ++j) rl[j] = 1.0f / __shfl(lrun, g * 4 + j, 64);

    float* Orow = O + ((size_t)b * 4096 + qb * 128 + w * 16) * 512;
#pragma unroll
    for (int ht = 0; ht < 32; ++ht)
#pragma unroll
        for (int j = 0; j < 4; ++j)
            Orow[(size_t)(g * 4 + j) * 512 + ht * 16 + r] = acc[ht][j] * rl[j];
}

// ---------- host ----------
extern "C" void kernel_launch(void* const* d_in, const int* in_sizes, int n_in,
                              void* d_out, int out_size, void* d_ws, size_t ws_size,
                              hipStream_t stream) {
    const float* tokens  = (const float*)d_in[0];
    const float* context = (const float*)d_in[1];
    const float* Wq      = (const float*)d_in[2];
    const float* Wk      = (const float*)d_in[3];
    const float* Wv      = (const float*)d_in[4];
    float* out = (float*)d_out;

    __bf16* WqT = (__bf16*)d_ws;                        // 512*512
    __bf16* WkT = WqT + (size_t)262144;                 // 512*768
    __bf16* WvT = WkT + (size_t)393216;                 // 512*768
    __bf16* Qws = WvT + (size_t)393216;                 // 32768*512
    __bf16* Kws = Qws + (size_t)16777216;               // 8192*512
    __bf16* VTw = Kws + (size_t)4194304;                // 8*32*512*32

    wtrans_all<<<4096, 256, 0, stream>>>(Wq, Wk, Wv, WqT, WkT, WvT);

    gemm128<0, true><<<dim3(4, 256), 256, 0, stream>>>(tokens,  WqT, Qws, 512, 0, 0);
    gemm128<0, true><<<dim3(4, 64),  256, 0, stream>>>(context, WkT, Kws, 768, 0, 0);
    gemm128<1, false><<<dim3(8, 4, 8), 256, 0, stream>>>(WvT, context, VTw, 768, 0,
                                                         (size_t)1024 * 768);

    flash_kernel<<<dim3(32, 8), 512, 0, stream>>>(Qws, Kws, VTw, out);
}

// Round 11
// 214.029 us; speedup vs baseline: 4.1268x; 4.1268x over previous
//
#include <hip/hip_runtime.h>
#include <hip/hip_bf16.h>

// ---------- types ----------
typedef __bf16 bf16x8 __attribute__((ext_vector_type(8)));
typedef float  f32x4  __attribute__((ext_vector_type(4)));
typedef float  f32x4v __attribute__((ext_vector_type(4)));

#define LOG2E 1.44269504088896340736f

static __device__ __forceinline__ f32x4 mfma16(bf16x8 a, bf16x8 b, f32x4 c) {
    return __builtin_amdgcn_mfma_f32_16x16x32_bf16(a, b, c, 0, 0, 0);
}

static __device__ __forceinline__ void gload_lds16(const void* g, void* lds) {
    __builtin_amdgcn_global_load_lds(
        (const __attribute__((address_space(1))) void*)g,
        (__attribute__((address_space(3))) void*)lds, 16, 0, 0);
}

// ---------- fused weight transpose (all three), bf16 ----------
// Wq [512][512] scaled; Wk,Wv [768][512]. grid 4096*256 == 1048576.
__global__ void wtrans_all(const float* __restrict__ Wq, const float* __restrict__ Wk,
                           const float* __restrict__ Wv, __bf16* __restrict__ WqT,
                           __bf16* __restrict__ WkT, __bf16* __restrict__ WvT) {
    int idx = blockIdx.x * 256 + threadIdx.x;
    if (idx < 262144) {
        int k = idx >> 9, n = idx & 511;
        WqT[(size_t)n * 512 + k] = (__bf16)(Wq[idx] * 0.044194173824159216f);
    } else if (idx < 655360) {
        int i = idx - 262144;
        int k = i >> 9, n = i & 511;
        WkT[(size_t)n * 768 + k] = (__bf16)Wk[i];
    } else {
        int i = idx - 655360;
        int k = i >> 9, n = i & 511;
        WvT[(size_t)n * 768 + k] = (__bf16)Wv[i];
    }
}

// ---------- 128x128-tile GEMM, BK=64, dbuf; one operand f32 (reg-staged + cvt),
// the other bf16 (global_load_lds). C[m][n] = sum_k A[m][k]*B[n][k].
// AF32: A is the f32 side (else B). MODE 0: C bf16 [M][512]. MODE 1: VT layout.
template<int MODE, bool AF32>
__global__ __launch_bounds__(256, 2) void gemm128(
    const void* __restrict__ Ap, const void* __restrict__ Bp,
    __bf16* __restrict__ C, int Ktot, size_t sAz, size_t sBz) {
    __shared__ char smem[65536];
    const int tid = threadIdx.x, w = tid >> 6, lane = tid & 63;
    const int r = lane & 15, g = lane >> 4;
    const int wr = w >> 1, wc = w & 1;
    const int m0 = blockIdx.y * 128, n0 = blockIdx.x * 128;
    const int z = blockIdx.z;

    // F = f32 side (reg-staged), G = bf16 side (gload_lds)
    const float*  F = AF32 ? (const float*)Ap + sAz * z : (const float*)Bp + sBz * z;
    const __bf16* G = AF32 ? (const __bf16*)Bp + sBz * z : (const __bf16*)Ap + sAz * z;
    const int Fbase = AF32 ? m0 : n0;
    const int Gbase = AF32 ? n0 : m0;

    f32x4 acc[4][4];
#pragma unroll
    for (int i = 0; i < 4; ++i)
#pragma unroll
        for (int j = 0; j < 4; ++j) acc[i][j] = (f32x4){0.f, 0.f, 0.f, 0.f};

    const int nsteps = Ktot >> 6;
    f32x4v rg[8];

    auto ISSUE = [&](int t) {
        int k0 = t * 64;
#pragma unroll
        for (int e = 0; e < 4; ++e) {           // 8 global f32x4 loads (F side)
            int flat = tid + e * 256;
            int row = flat >> 3, blk = flat & 7;
            const float* gp = F + (size_t)(Fbase + row) * Ktot + k0 + blk * 8;
            rg[2 * e]     = *(const f32x4v*)gp;
            rg[2 * e + 1] = *(const f32x4v*)(gp + 4);
        }
        char* bufG = smem + (t & 1) * 32768 + (AF32 ? 16384 : 0);
#pragma unroll
        for (int e = 0; e < 4; ++e) {           // 4 gload_lds (G side)
            int rows8 = w * 32 + e * 8;
            int row = rows8 + (lane >> 3);
            int so = ((lane & 7) ^ (row & 7)) << 4;
            gload_lds16((const char*)(G + (size_t)(Gbase + row) * Ktot + k0) + so,
                        bufG + rows8 * 128);
        }
    };
    auto WRITE = [&](int t) {
        char* bufF = smem + (t & 1) * 32768 + (AF32 ? 0 : 16384);
#pragma unroll
        for (int e = 0; e < 4; ++e) {
            int flat = tid + e * 256;
            int row = flat >> 3, blk = flat & 7;
            bf16x8 v;
            v[0] = (__bf16)rg[2 * e][0]; v[1] = (__bf16)rg[2 * e][1];
            v[2] = (__bf16)rg[2 * e][2]; v[3] = (__bf16)rg[2 * e][3];
            v[4] = (__bf16)rg[2 * e + 1][0]; v[5] = (__bf16)rg[2 * e + 1][1];
            v[6] = (__bf16)rg[2 * e + 1][2]; v[7] = (__bf16)rg[2 * e + 1][3];
            *(bf16x8*)(bufF + row * 128 + ((blk ^ (row & 7)) << 4)) = v;
        }
    };

    ISSUE(0);
#pragma unroll 1
    for (int t = 0; t < nsteps; ++t) {
        __builtin_amdgcn_s_barrier();                       // buf[(t+1)&1] free
        asm volatile("s_waitcnt vmcnt(4)" ::: "memory");    // F(t) reg-loads landed
        WRITE(t);
        if (t + 1 < nsteps) {
            ISSUE(t + 1);
            asm volatile("s_waitcnt vmcnt(12)" ::: "memory"); // G(t) gloads landed
        } else {
            asm volatile("s_waitcnt vmcnt(0)" ::: "memory");
        }
        asm volatile("s_waitcnt lgkmcnt(0)" ::: "memory");    // ds_writes visible
        __builtin_amdgcn_s_barrier();                       // tile t ready
        __builtin_amdgcn_sched_barrier(0);

        char* bufA = smem + (t & 1) * 32768;
        char* bufB = bufA + 16384;
#pragma unroll
        for (int c = 0; c < 2; ++c) {
            bf16x8 a[4], bb[4];
#pragma unroll
            for (int mt = 0; mt < 4; ++mt) {
                int ar = wr * 64 + mt * 16 + r;
                a[mt] = *(const bf16x8*)(bufA + ar * 128 + (((c * 4 + g) ^ (ar & 7)) << 4));
            }
#pragma unroll
            for (int nt = 0; nt < 4; ++nt) {
                int br = wc * 64 + nt * 16 + r;
                bb[nt] = *(const bf16x8*)(bufB + br * 128 + (((c * 4 + g) ^ (br & 7)) << 4));
            }
            __builtin_amdgcn_s_setprio(1);
#pragma unroll
            for (int mt = 0; mt < 4; ++mt)
#pragma unroll
                for (int nt = 0; nt < 4; ++nt)
                    acc[mt][nt] = mfma16(a[mt], bb[nt], acc[mt][nt]);
            __builtin_amdgcn_s_setprio(0);
        }
    }

#pragma unroll
    for (int mt = 0; mt < 4; ++mt)
#pragma unroll
        for (int nt = 0; nt < 4; ++nt)
#pragma unroll
            for (int j = 0; j < 4; ++j) {
                int m = m0 + wr * 64 + mt * 16 + g * 4 + j;
                int n = n0 + wc * 64 + nt * 16 + r;
                if (MODE == 0) {
                    C[(size_t)m * 512 + n] = (__bf16)acc[mt][nt][j];
                } else {
                    int l = n & 31;
                    int perm = ((l >> 2) & 3) * 8 + ((l >> 4) & 1) * 4 + (l & 3);
                    C[(((size_t)z * 32 + (n >> 5)) * 512 + m) * 32 + perm] =
                        (__bf16)acc[mt][nt][j];
                }
            }
}

// ---------- flash attention ----------
// r7 skeleton EXACTLY (proven: 155 us, FETCH/WRITE at ideal) + two
// zero-live-state softmax cuts:
//   (1) bit-exact rescale skip: __all(mt <= mrun) => mnew==mrun, corr==1;
//       branch around 128 acc-mults + 4 shuffles (fires most iters).
//   (2) deferred l-sum: per-lane partial lpart, butterfly once at epilogue
//       (removes 2 shfl_xor per iter from the serial softmax window).
// grid (32, 8): qb = blockIdx.x, b = blockIdx.y. KVBLK=32, double-buffered.
// LDS 128 KB: 2 bufs x { K [32 s][1024B] swz ^((row&7)<<4) |
//                        VT [512 h][64B] interleaved-s, blk swz ^((vrow>>1)&3) }.
// r4/r6/r10 lesson: NO carried per-iteration state beyond {mrun, lpart} —
// the register file is exactly full (acc 128 AGPR + q 64 VGPR + working set).
__global__ __launch_bounds__(512, 2) void flash_kernel(
    const __bf16* __restrict__ Q,    // [B*4096][512] (pre-scaled by 1/sqrt(512))
    const __bf16* __restrict__ Kg,   // [B*1024][512]
    const __bf16* __restrict__ VT,   // [B][32][512 h][32 s interleaved]
    float* __restrict__ O) {         // [B*4096][512]
    __shared__ char smem[131072];

    const int tid = threadIdx.x, w = tid >> 6, lane = tid & 63;
    const int r = lane & 15, g = lane >> 4;
    const int b = blockIdx.y, qb = blockIdx.x;

    const __bf16* Qrow = Q + ((size_t)b * 4096 + qb * 128 + w * 16 + r) * 512;
    bf16x8 q[16];
#pragma unroll
    for (int c = 0; c < 16; ++c) q[c] = *(const bf16x8*)(Qrow + c * 32 + g * 8);

    f32x4 acc[32];
#pragma unroll
    for (int i = 0; i < 32; ++i) acc[i] = (f32x4){0.f, 0.f, 0.f, 0.f};

    float mrun = -__builtin_inff(), lpart = 0.f;

    const size_t kbase = (size_t)b * 1024 * 512;
    const char*  vbase = (const char*)(VT + (size_t)b * 32 * 16384);

    auto STAGE = [&](int it) {
        char* bufc = smem + (it & 1) * 65536;
        const char* ksrc = (const char*)(Kg + kbase + (size_t)it * 32 * 512);
#pragma unroll
        for (int e = 0; e < 4; ++e) {
            int row = w * 4 + e;
            gload_lds16(ksrc + row * 1024 + ((lane * 16) ^ ((row & 7) << 4)),
                        bufc + row * 1024);
        }
        const char* vtile = vbase + (size_t)it * 32768;
#pragma unroll
        for (int e = 0; e < 4; ++e) {
            int flat = e * 512 + w * 64 + lane;
            int vrow = flat >> 2, blk = flat & 3;
            gload_lds16(vtile + vrow * 64 + ((blk ^ ((vrow >> 1) & 3)) << 4),
                        bufc + 32768 + e * 8192 + w * 1024);   // +lane*16 by HW
        }
    };

    STAGE(0);
#pragma unroll 1
    for (int it = 0; it < 32; ++it) {
        __builtin_amdgcn_s_barrier();                  // buf[(it+1)&1] readers done
        if (it < 31) {
            STAGE(it + 1);
            asm volatile("s_waitcnt vmcnt(8)" ::: "memory");  // tile-it landed
        } else {
            asm volatile("s_waitcnt vmcnt(0)" ::: "memory");
        }
        __builtin_amdgcn_s_barrier();                  // all waves' tile-it landed
        __builtin_amdgcn_sched_barrier(0);

        char* Kt = smem + (it & 1) * 65536;
        char* Vt = Kt + 32768;

        // swapped QK^T: S^T[s][q] = mfma(Kfrag, Qfrag); q = r, s: sc0->4g+j, sc1->16+4g+j
        f32x4 sc0 = (f32x4){0.f, 0.f, 0.f, 0.f};
        f32x4 sc1 = (f32x4){0.f, 0.f, 0.f, 0.f};
        const int sw = (r & 7) << 4;   // (r+16)&7 == r&7
        __builtin_amdgcn_s_setprio(1);
#pragma unroll
        for (int c = 0; c < 16; ++c) {
            int bir = (c * 64 + g * 16) ^ sw;
            bf16x8 k0 = *(const bf16x8*)(Kt + r * 1024 + bir);
            bf16x8 k1 = *(const bf16x8*)(Kt + (r + 16) * 1024 + bir);
            sc0 = mfma16(k0, q[c], sc0);
            sc1 = mfma16(k1, q[c], sc1);
        }
        __builtin_amdgcn_s_setprio(0);

        // online softmax for q = r; bit-exact skip when no row max grew
        float mt = fmaxf(fmaxf(fmaxf(sc0[0], sc0[1]), fmaxf(sc0[2], sc0[3])),
                         fmaxf(fmaxf(sc1[0], sc1[1]), fmaxf(sc1[2], sc1[3])));
        mt = fmaxf(mt, __shfl_xor(mt, 16, 64));
        mt = fmaxf(mt, __shfl_xor(mt, 32, 64));

        const bool skip = __all(mt <= mrun);           // skip => mnew==mrun, corr==1
        const float mnew = skip ? mrun : fmaxf(mrun, mt);
        float p0[4], p1[4], ps = 0.f;
#pragma unroll
        for (int j = 0; j < 4; ++j) {
            p0[j] = exp2f((sc0[j] - mnew) * LOG2E);
            p1[j] = exp2f((sc1[j] - mnew) * LOG2E);
            ps += p0[j] + p1[j];
        }
        if (skip) {
            lpart += ps;                               // own-lane partial only
        } else {
            float corr = exp2f((mrun - mnew) * LOG2E);
            lpart = lpart * corr + ps;
            mrun = mnew;
            float corr4[4];
#pragma unroll
            for (int j = 0; j < 4; ++j) corr4[j] = __shfl(corr, g * 4 + j, 64);
#pragma unroll
            for (int ht = 0; ht < 32; ++ht) {
                acc[ht][0] *= corr4[0]; acc[ht][1] *= corr4[1];
                acc[ht][2] *= corr4[2]; acc[ht][3] *= corr4[3];
            }
        }

        union { bf16x8 v; __bf16 e[8]; } pa;
#pragma unroll
        for (int j = 0; j < 4; ++j) { pa.e[j] = (__bf16)p0[j]; pa.e[4 + j] = (__bf16)p1[j]; }

        // PV: one b128 per h-row (interleaved VT), swizzle ^((vrow>>1)&3) on blk
        __builtin_amdgcn_s_setprio(1);
#pragma unroll
        for (int ht = 0; ht < 32; ++ht) {
            int vrow = ht * 16 + r;
            bf16x8 bv = *(const bf16x8*)(Vt + vrow * 64 + ((g ^ ((r >> 1) & 3)) << 4));
            acc[ht] = mfma16(pa.v, bv, acc[ht]);
        }
        __builtin_amdgcn_s_setprio(0);
    }

    // epilogue: butterfly the deferred l partials (once), then normalize
    float lsum = lpart;
    lsum += __shfl_xor(lsum, 16, 64);
    lsum += __shfl_xor(lsum, 32, 64);
    float rl[4];
#pragma unroll
    for (int j = 0; j < 4; ++j) rl[j] = 1.0f / __shfl(lsum, g * 4 + j, 64);

    float* Orow = O + ((size_t)b * 4096 + qb * 128 + w * 16) * 512;
#pragma unroll
    for (int ht = 0; ht < 32; ++ht)
#pragma unroll
        for (int j = 0; j < 4; ++j)
            Orow[(size_t)(g * 4 + j) * 512 + ht * 16 + r] = acc[ht][j] * rl[j];
}

// ---------- host ----------
extern "C" void kernel_launch(void* const* d_in, const int* in_sizes, int n_in,
                              void* d_out, int out_size, void* d_ws, size_t ws_size,
                              hipStream_t stream) {
    const float* tokens  = (const float*)d_in[0];
    const float* context = (const float*)d_in[1];
    const float* Wq      = (const float*)d_in[2];
    const float* Wk      = (const float*)d_in[3];
    const float* Wv      = (const float*)d_in[4];
    float* out = (float*)d_out;

    __bf16* WqT = (__bf16*)d_ws;                        // 512*512
    __bf16* WkT = WqT + (size_t)262144;                 // 512*768
    __bf16* WvT = WkT + (size_t)393216;                 // 512*768
    __bf16* Qws = WvT + (size_t)393216;                 // 32768*512
    __bf16* Kws = Qws + (size_t)16777216;               // 8192*512
    __bf16* VTw = Kws + (size_t)4194304;                // 8*32*512*32

    wtrans_all<<<4096, 256, 0, stream>>>(Wq, Wk, Wv, WqT, WkT, WvT);

    gemm128<0, true><<<dim3(4, 256), 256, 0, stream>>>(tokens,  WqT, Qws, 512, 0, 0);
    gemm128<0, true><<<dim3(4, 64),  256, 0, stream>>>(context, WkT, Kws, 768, 0, 0);
    gemm128<1, false><<<dim3(8, 4, 8), 256, 0, stream>>>(WvT, context, VTw, 768, 0,
                                                         (size_t)1024 * 768);

    flash_kernel<<<dim3(32, 8), 512, 0, stream>>>(Qws, Kws, VTw, out);
}